// Round 9
// baseline (3372.149 us; speedup 1.0000x reference)
//
#include <hip/hip_runtime.h>
#include <hip/hip_bf16.h>
#include <math.h>

#define NNODE 200000
#define EMBD  128
#define TT    32
#define EE    100000
#define AA    4096
#define BB    2048
#define USERN 150000
#define COMPN 49998
#define NPAD  50048     // 391*128
#define NT2   391       // lse n-tiles of 128
#define NT2P  392
#define WLMAX 100096    // >= max touched rows/step (<=100000), mult of 8
#define GATHB (WLMAX / 8)
#define SCAN_N (TT * NNODE)          // 6,400,000
#define SCAN_ITEMS 1024
#define SCAN_BLKS (SCAN_N / SCAN_ITEMS)   // 6250 exact

typedef __attribute__((ext_vector_type(8))) short short8;
typedef __attribute__((ext_vector_type(4))) float f32x4;
typedef unsigned short ushort_t;

__device__ __forceinline__ ushort_t f2bf(float f) {
    unsigned u = __float_as_uint(f);
    unsigned r = (u + 0x7fffu + ((u >> 16) & 1u)) >> 16;   // RNE
    return (ushort_t)r;
}
__device__ __forceinline__ unsigned pack2bf(float lo, float hi) {
    return ((unsigned)f2bf(hi) << 16) | (unsigned)f2bf(lo);
}
__device__ __forceinline__ float bflo(unsigned p) { return __uint_as_float(p << 16); }
__device__ __forceinline__ float bfhi(unsigned p) { return __uint_as_float(p & 0xffff0000u); }
__device__ __forceinline__ float bf2f(ushort_t b) { return __uint_as_float((unsigned)b << 16); }
__device__ __forceinline__ float sig(float x) { return 1.f / (1.f + __expf(-x)); }

// ---------------- init A: node16 convert, zero deg/aslot/wl_n/out ----------------
__global__ void init_a(const float4* __restrict__ ent, ushort_t* __restrict__ node16,
                       int* __restrict__ deg, int* __restrict__ aslot,
                       int* __restrict__ wl_n, float* __restrict__ out) {
    const long NV = (long)NNODE * EMBD / 4;
    long i0 = (long)blockIdx.x * blockDim.x + threadIdx.x;
    long stride = (long)gridDim.x * blockDim.x;
    uint2* n2 = (uint2*)node16;
    for (long i = i0; i < NV; i += stride) {
        float4 v = ent[i];
        n2[i] = make_uint2(pack2bf(v.x, v.y), pack2bf(v.z, v.w));
    }
    for (long i = i0; i < SCAN_N; i += stride) deg[i] = 0;
    for (long i = i0; i < NNODE; i += stride) aslot[i] = 0;
    for (long i = i0; i < TT; i += stride) wl_n[i] = 0;
    if (i0 == 0) out[0] = 0.f;
}

// ---------------- once: convert weights/biases/comp emb; stamp act step0 ----------------
__global__ void convert_kernel(const float* __restrict__ Wih, const float* __restrict__ Whh,
                               const float* __restrict__ bih, const float* __restrict__ bhh,
                               const float* __restrict__ ent, const int* __restrict__ act,
                               short* __restrict__ w16, float* __restrict__ bsum,
                               short* __restrict__ c16, int* __restrict__ aslot) {
    long i0 = (long)blockIdx.x * blockDim.x + threadIdx.x;
    long stride = (long)gridDim.x * blockDim.x;
    for (long i = i0; i < 512 * 256; i += stride) {
        int n = i >> 8, k = i & 255;
        float v = (k < 128) ? Wih[(size_t)n * 128 + k] : Whh[(size_t)n * 128 + (k - 128)];
        w16[i] = (short)f2bf(v);
    }
    for (long i = i0; i < 512; i += stride) bsum[i] = bih[i] + bhh[i];
    for (long i = i0; i < (long)NPAD * 128; i += stride) {
        long r = i >> 7;
        float v = (r < COMPN) ? ent[(size_t)(USERN + r) * 128 + (i & 127)] : 0.f;
        c16[i] = (short)f2bf(v);
    }
    for (long i = i0; i < AA; i += stride) aslot[act[i]] = (1 << 12) | (int)i;
}

// ---------------- once: histogram edges per (t,dst) ----------------
__global__ void hist_kernel(const int* __restrict__ edst_all, int* __restrict__ deg) {
    int i = blockIdx.x * 256 + threadIdx.x;            // < TT*EE
    int t = i / EE;
    atomicAdd(&deg[(long)t * NNODE + edst_all[i]], 1);
}

// ---------------- once: prefix scan (3 passes) ----------------
__global__ __launch_bounds__(256) void scan1(const int* __restrict__ deg,
                                             int* __restrict__ rs, int* __restrict__ bsums) {
    __shared__ int sh[256];
    long base = (long)blockIdx.x * SCAN_ITEMS;
    int tid = threadIdx.x;
    long idx = base + tid * 4;
    int4 v = *(const int4*)&deg[idx];
    int s0 = v.x, s1 = s0 + v.y, s2 = s1 + v.z, s3 = s2 + v.w;
    sh[tid] = s3; __syncthreads();
    for (int off = 1; off < 256; off <<= 1) {
        int t2 = (tid >= off) ? sh[tid - off] : 0; __syncthreads();
        sh[tid] += t2; __syncthreads();
    }
    int excl = tid ? sh[tid - 1] : 0;
    int4 o; o.x = excl; o.y = excl + s0; o.z = excl + s1; o.w = excl + s2;
    *(int4*)&rs[idx] = o;
    if (tid == 255) bsums[blockIdx.x] = sh[255];
}

__global__ __launch_bounds__(256) void scan2(int* __restrict__ bsums) {
    __shared__ int sh[256];
    __shared__ int roff;
    int tid = threadIdx.x;
    if (tid == 0) roff = 0;
    __syncthreads();
    for (int c = 0; c < SCAN_BLKS; c += 256) {
        int v = (c + tid < SCAN_BLKS) ? bsums[c + tid] : 0;
        sh[tid] = v; __syncthreads();
        for (int off = 1; off < 256; off <<= 1) {
            int t2 = (tid >= off) ? sh[tid - off] : 0; __syncthreads();
            sh[tid] += t2; __syncthreads();
        }
        int excl = (tid ? sh[tid - 1] : 0) + roff;
        int tot = sh[255];
        if (c + tid < SCAN_BLKS) bsums[c + tid] = excl;
        __syncthreads();
        if (tid == 0) roff += tot;
        __syncthreads();
    }
}

// add block offsets, copy cursors, build worklists (wave-aggregated appends)
__global__ __launch_bounds__(256) void scan3(const int* __restrict__ deg, int* __restrict__ rs,
                                             const int* __restrict__ bsums, int* __restrict__ cur,
                                             int* __restrict__ wl, int* __restrict__ wl_n) {
    long base = (long)blockIdx.x * SCAN_ITEMS;
    int off = bsums[blockIdx.x];
    int tid = threadIdx.x;
    int lane = tid & 63;
    long idx = base + tid * 4;
    int4 r = *(int4*)&rs[idx];
    r.x += off; r.y += off; r.z += off; r.w += off;
    *(int4*)&rs[idx] = r;
    *(int4*)&cur[idx] = r;
    int4 d = *(const int4*)&deg[idx];
    int dv[4] = {d.x, d.y, d.z, d.w};
#pragma unroll
    for (int j = 0; j < 4; ++j) {
        long i = idx + j;
        int t0 = (int)(i / NNODE);
        int vv = (int)(i - (long)t0 * NNODE);
        bool has = dv[j] > 0;
        unsigned long long m_all = __ballot(has);
        while (m_all) {
            int ld = __ffsll((long long)m_all) - 1;
            int tl = __shfl(t0, ld);
            unsigned long long grp = __ballot(has && t0 == tl);
            int cnt = __popcll(grp);
            int basep = 0;
            if (lane == ld) basep = atomicAdd(&wl_n[tl], cnt);
            basep = __shfl(basep, ld);
            if (has && t0 == tl) {
                int rank = __popcll(grp & ((1ULL << lane) - 1ULL));
                wl[(size_t)tl * WLMAX + basep + rank] = vv;
            }
            m_all &= ~grp;
        }
    }
}

// ---------------- once: scatter src ids into CSR lists ----------------
__global__ void scatter_kernel(const int* __restrict__ esrc_all, const int* __restrict__ edst_all,
                               int* __restrict__ cur, int* __restrict__ eidx) {
    int i = blockIdx.x * 256 + threadIdx.x;            // < TT*EE
    int t = i / EE;
    int pos = atomicAdd(&cur[(long)t * NNODE + edst_all[i]], 1);
    eidx[pos] = esrc_all[i];
}

// ---------------- per-step K1: gather sums (read-only node) || snapshot(t-1) || stamp t+1 ----
__global__ __launch_bounds__(512) void gather_snap(const int* __restrict__ wl,
                                                   const int* __restrict__ wl_n,
                                                   const int* __restrict__ rs,
                                                   const int* __restrict__ deg,
                                                   const int* __restrict__ eidx,
                                                   const ushort_t* __restrict__ node16,
                                                   int* __restrict__ aslot,
                                                   ushort_t* __restrict__ aggW,
                                                   float* __restrict__ aggA,
                                                   const int* __restrict__ su,
                                                   const int* __restrict__ st,
                                                   float* __restrict__ u_emb,
                                                   ushort_t* __restrict__ u16,
                                                   const int* __restrict__ act_all, int t) {
    int blk = blockIdx.x, tid = threadIdx.x;
    if (blk < GATHB) {
        int p = blk * 8 + (tid >> 6);
        if (p >= wl_n[t]) return;
        int lane = tid & 63;
        int v = wl[(size_t)t * WLMAX + p];
        long fi = (long)t * NNODE + v;
        int dg = deg[fi];
        int s0 = rs[fi];
        float sx = 0.f, sy = 0.f;
        for (int j = 0; j < dg; ++j) {
            int s = eidx[s0 + j];
            unsigned pair = ((const unsigned*)node16)[(size_t)s * 64 + lane];
            sx += bflo(pair); sy += bfhi(pair);
        }
        int a = aslot[v];
        if ((a >> 12) == t + 1) {
            *(float2*)&aggA[(size_t)(a & 4095) * 128 + lane * 2] = make_float2(sx, sy);
        } else {
            ((unsigned*)aggW)[(size_t)p * 64 + lane] = pack2bf(sx, sy);
        }
    } else if (blk < GATHB + 256) {
        if (t == 0) return;
        int b = (blk - GATHB) * 8 + (tid >> 6);
        int lane = tid & 63;
        if (st[b] == t - 1) {
            unsigned pair = ((const unsigned*)node16)[(size_t)su[b] * 64 + lane];
            ((unsigned*)u16)[(size_t)b * 64 + lane] = pair;
            *(float2*)&u_emb[(size_t)b * 128 + lane * 2] = make_float2(bflo(pair), bfhi(pair));
        }
    } else {
        if (t + 1 >= TT) return;
        int i = (blk - GATHB - 256) * 512 + tid;
        if (i < AA) aslot[act_all[(size_t)(t + 1) * AA + i]] = ((t + 2) << 12) | i;
    }
}

// ---------------- per-step K2: [gates MFMA + LSTM epi] (blk<256) || apply (rest) ----------
__global__ __launch_bounds__(512) void apply_gates(const int* __restrict__ wl,
                                                   const int* __restrict__ wl_n,
                                                   const int* __restrict__ deg,
                                                   const int* __restrict__ aslot,
                                                   const ushort_t* __restrict__ aggW,
                                                   const float* __restrict__ aggA,
                                                   ushort_t* node16,
                                                   const short* __restrict__ w16,
                                                   const float* __restrict__ bsum,
                                                   const int* __restrict__ act_t,
                                                   const float* __restrict__ c0, int t) {
    __shared__ ushort_t XH[16 * 256];   // 8 KB, XOR-swizzled 16B chunks
    int blk = blockIdx.x, tid = threadIdx.x;
    if (blk < 256) {
        int m0 = blk * 16;
        {
            int row = tid >> 5, j = tid & 31, ch = j & 15;
            int v = act_t[m0 + row];
            int sw = ch ^ (row & 7);
            uint4 nd = *(const uint4*)(node16 + (size_t)v * 128 + ch * 8);
            if (j < 16) {
                int dg = deg[(long)t * NNODE + v];
                uint4 xx = nd;
                if (dg > 0) {
                    float rc = 1.f / dg;
                    float4 A0 = *(const float4*)&aggA[(size_t)(m0 + row) * 128 + ch * 8];
                    float4 A1 = *(const float4*)&aggA[(size_t)(m0 + row) * 128 + ch * 8 + 4];
                    xx.x = pack2bf(bflo(nd.x) + A0.x * rc, bfhi(nd.x) + A0.y * rc);
                    xx.y = pack2bf(bflo(nd.y) + A0.z * rc, bfhi(nd.y) + A0.w * rc);
                    xx.z = pack2bf(bflo(nd.z) + A1.x * rc, bfhi(nd.z) + A1.y * rc);
                    xx.w = pack2bf(bflo(nd.w) + A1.z * rc, bfhi(nd.w) + A1.w * rc);
                }
                *(uint4*)((char*)XH + row * 512 + (sw << 4)) = xx;
            } else {
                *(uint4*)((char*)XH + row * 512 + ((16 + sw) << 4)) = nd;   // prev_h
            }
        }
        __syncthreads();
        int w = tid >> 6, lane = tid & 63;
        int la = lane & 15, lb = lane >> 4;
        f32x4 acc[4] = {};
#pragma unroll
        for (int kc = 0; kc < 8; ++kc) {
            int cc = kc * 4 + lb;
            int sc = (cc & 16) | ((cc & 15) ^ (la & 7));
            short8 af = *(const short8*)((char*)XH + la * 512 + (sc << 4));
#pragma unroll
            for (int s = 0; s < 4; ++s) {
                int n = s * 128 + w * 16 + la;
                short8 bf = *(const short8*)&w16[(size_t)n * 256 + kc * 32 + lb * 8];
                acc[s] = __builtin_amdgcn_mfma_f32_16x16x32_bf16(af, bf, acc[s], 0, 0, 0);
            }
        }
        int d = w * 16 + la;
        float b_i = bsum[d], b_f = bsum[128 + d], b_g = bsum[256 + d], b_o = bsum[384 + d];
#pragma unroll
        for (int r = 0; r < 4; ++r) {
            int lrow = lb * 4 + r;
            int v = act_t[m0 + lrow];
            float gi = acc[0][r] + b_i;
            float gf = acc[1][r] + b_f;
            float gg = acc[2][r] + b_g;
            float go = acc[3][r] + b_o;
            float pc = c0[(size_t)v * 128 + d];      // each node active at most once -> prev_c = c0
            float c_ = sig(gf) * pc + sig(gi) * tanhf(gg);
            float h_ = sig(go) * tanhf(c_);
            node16[(size_t)v * 128 + d] = f2bf(h_);
        }
    } else {
        int p = (blk - 256) * 8 + (tid >> 6);
        if (p >= wl_n[t]) return;
        int lane = tid & 63;
        int v = wl[(size_t)t * WLMAX + p];
        int a = aslot[v];
        if ((a >> 12) == t + 1) return;              // act row handled by gates
        int dg = deg[(long)t * NNODE + v];
        float rc = 1.f / dg;
        unsigned wv = ((const unsigned*)aggW)[(size_t)p * 64 + lane];
        unsigned n = ((unsigned*)node16)[(size_t)v * 64 + lane];
        ((unsigned*)node16)[(size_t)v * 64 + lane] =
            pack2bf(bflo(n) + bflo(wv) * rc, bfhi(n) + bfhi(wv) * rc);
    }
}

// ---------------- post-loop: snapshot t=31 ----------------
__global__ __launch_bounds__(256) void snap31(const ushort_t* __restrict__ node16,
                                              const int* __restrict__ su,
                                              const int* __restrict__ st,
                                              float* __restrict__ u_emb,
                                              ushort_t* __restrict__ u16) {
    int b = blockIdx.x * 2 + threadIdx.x / 128;
    int d = threadIdx.x % 128;
    if (st[b] == TT - 1) {
        ushort_t hv = node16[(size_t)su[b] * 128 + d];
        u16[(size_t)b * 128 + d] = hv;
        u_emb[(size_t)b * 128 + d] = bf2f(hv);
    }
}

// ---------------- final: bf16 MFMA LSE partials, LDS-staged B, tile-major partials ----------
__global__ __launch_bounds__(512) void lse_mfma(const short* __restrict__ u16,
                                                const short* __restrict__ c16,
                                                float* __restrict__ pm, float* __restrict__ ps) {
    __shared__ short Bs[128 * 128];   // 32 KB
    int n0 = blockIdx.x * 128;
    int tid = threadIdx.x;
    const uint4* gsrc = (const uint4*)&c16[(size_t)n0 * 128];
#pragma unroll
    for (int j = 0; j < 4; ++j) {
        int c = j * 512 + tid;
        int r = c >> 4, cc = c & 15;
        *(uint4*)((char*)Bs + r * 256 + ((cc ^ (r & 7)) << 4)) = gsrc[c];
    }
    __syncthreads();

    int w = tid >> 6;
    int lane = tid & 63;
    int la = lane & 15, lb = lane >> 4;
    for (int mt = blockIdx.y * 8; mt < blockIdx.y * 8 + 8; ++mt) {
        int m_a = mt * 128 + w * 16 + la;
        f32x4 acc[8] = {};
#pragma unroll
        for (int kc = 0; kc < 4; ++kc) {
            short8 af = *(const short8*)&u16[(size_t)m_a * 128 + kc * 32 + lb * 8];
#pragma unroll
            for (int s = 0; s < 8; ++s) {
                int nl = s * 16 + la;
                short8 bf = *(const short8*)((const char*)Bs + nl * 256 +
                                             (((kc * 4 + lb) ^ (nl & 7)) << 4));
                acc[s] = __builtin_amdgcn_mfma_f32_16x16x32_bf16(af, bf, acc[s], 0, 0, 0);
            }
        }
#pragma unroll
        for (int r = 0; r < 4; ++r) {
            int row = mt * 128 + w * 16 + lb * 4 + r;
            float mx = -3.4e38f;
#pragma unroll
            for (int s = 0; s < 8; ++s)
                if (n0 + s * 16 + la < COMPN) mx = fmaxf(mx, acc[s][r]);
#pragma unroll
            for (int off = 1; off < 16; off <<= 1) mx = fmaxf(mx, __shfl_xor(mx, off));
            float sm = 0.f;
#pragma unroll
            for (int s = 0; s < 8; ++s)
                if (n0 + s * 16 + la < COMPN) sm += __expf(acc[s][r] - mx);
#pragma unroll
            for (int off = 1; off < 16; off <<= 1) sm += __shfl_xor(sm, off);
            if (la == 0) {
                pm[(size_t)blockIdx.x * BB + row] = mx;   // tile-major: contiguous writes
                ps[(size_t)blockIdx.x * BB + row] = sm;
            }
        }
    }
}

// ---------------- final: wave-per-row merge + pos dot + loss ----------------
__global__ __launch_bounds__(256) void merge_final(const float* __restrict__ pm,
                                                   const float* __restrict__ ps,
                                                   const float* __restrict__ u_emb,
                                                   const float* __restrict__ ent,
                                                   const int* __restrict__ crel,
                                                   float* __restrict__ out) {
    int row = blockIdx.x * 4 + (threadIdx.x >> 6);
    int lane = threadIdx.x & 63;
    float m = -3.4e38f, s = 0.f;
    for (int c = lane; c < NT2; c += 64) {
        float mi = pm[(size_t)c * BB + row];
        float si = ps[(size_t)c * BB + row];
        float mn = fmaxf(m, mi);
        s = s * __expf(m - mn) + si * __expf(mi - mn);
        m = mn;
    }
#pragma unroll
    for (int off = 1; off < 64; off <<= 1) {
        float mo = __shfl_xor(m, off);
        float so = __shfl_xor(s, off);
        float mn = fmaxf(m, mo);
        s = s * __expf(m - mn) + so * __expf(mo - mn);
        m = mn;
    }
    float2 uv = *(const float2*)&u_emb[(size_t)row * 128 + lane * 2];
    float2 cv = *(const float2*)&ent[(size_t)(USERN + crel[row]) * 128 + lane * 2];
    float p = uv.x * cv.x + uv.y * cv.y;
#pragma unroll
    for (int off = 1; off < 64; off <<= 1) p += __shfl_xor(p, off);
    if (lane == 0) atomicAdd(out, m + logf(s) - p);
}

extern "C" void kernel_launch(void* const* d_in, const int* in_sizes, int n_in,
                              void* d_out, int out_size, void* d_ws, size_t ws_size,
                              hipStream_t stream) {
    const float* ent  = (const float*)d_in[0];
    const float* c0   = (const float*)d_in[1];
    const float* Wih  = (const float*)d_in[2];
    const float* Whh  = (const float*)d_in[3];
    const float* bih  = (const float*)d_in[4];
    const float* bhh  = (const float*)d_in[5];
    const int* esrc   = (const int*)d_in[6];
    const int* edst   = (const int*)d_in[7];
    const int* act    = (const int*)d_in[8];
    const int* susr   = (const int*)d_in[9];
    const int* stime  = (const int*)d_in[10];
    const int* crel   = (const int*)d_in[11];
    float* out = (float*)d_out;

    float* ws = (float*)d_ws;
    size_t o = 0;
    ushort_t* node16 = (ushort_t*)(ws + o); o += (size_t)NNODE * EMBD / 2;   // 51.2 MB
    int* deg  = (int*)(ws + o); o += SCAN_N;                                  // 25.6 MB
    int* rs   = (int*)(ws + o); o += SCAN_N;                                  // 25.6 MB
    int* cur  = (int*)(ws + o); o += SCAN_N;                                  // 25.6 MB
    int* eidx = (int*)(ws + o); o += (size_t)TT * EE;                         // 12.8 MB
    int* wl   = (int*)(ws + o); o += (size_t)TT * WLMAX;                      // 12.8 MB
    int* wl_n = (int*)(ws + o); o += 64;
    int* bsums = (int*)(ws + o); o += SCAN_BLKS;
    int* aslot = (int*)(ws + o); o += NNODE;
    ushort_t* aggW = (ushort_t*)(ws + o); o += (size_t)WLMAX * 128 / 2;       // 25.6 MB
    float* aggA = ws + o; o += (size_t)AA * 128;                              // 2 MB
    float* u_emb = ws + o; o += (size_t)BB * 128;
    ushort_t* u16 = (ushort_t*)(ws + o); o += (size_t)BB * 128 / 2;
    short* w16 = (short*)(ws + o); o += (size_t)512 * 256 / 2;
    float* bsum = ws + o; o += 512;
    short* c16 = (short*)(ws + o); o += (size_t)NPAD * 128 / 2;
    // lse partials reuse cur (idle post-loop)
    float* pm = (float*)cur;
    float* ps = pm + (size_t)BB * NT2P;

    // ---- one-time build ----
    init_a<<<4096, 256, 0, stream>>>((const float4*)ent, node16, deg, aslot, wl_n, out);
    convert_kernel<<<2048, 256, 0, stream>>>(Wih, Whh, bih, bhh, ent, act, w16, bsum, c16, aslot);
    hist_kernel<<<TT * EE / 256, 256, 0, stream>>>(edst, deg);
    scan1<<<SCAN_BLKS, 256, 0, stream>>>(deg, rs, bsums);
    scan2<<<1, 256, 0, stream>>>(bsums);
    scan3<<<SCAN_BLKS, 256, 0, stream>>>(deg, rs, bsums, cur, wl, wl_n);
    scatter_kernel<<<TT * EE / 256, 256, 0, stream>>>(esrc, edst, cur, eidx);

    // ---- time loop: 2 launches/step ----
    for (int t = 0; t < TT; ++t) {
        const int* act_t = act + (size_t)t * AA;
        gather_snap<<<GATHB + 256 + 8, 512, 0, stream>>>(wl, wl_n, rs, deg, eidx, node16,
                                                         aslot, aggW, aggA, susr, stime,
                                                         u_emb, u16, act, t);
        apply_gates<<<256 + GATHB, 512, 0, stream>>>(wl, wl_n, deg, aslot, aggW, aggA,
                                                     node16, w16, bsum, act_t, c0, t);
    }

    snap31<<<BB / 2, 256, 0, stream>>>(node16, susr, stime, u_emb, u16);
    lse_mfma<<<dim3(NT2, 2), 512, 0, stream>>>((const short*)u16, c16, pm, ps);
    merge_final<<<BB / 4, 256, 0, stream>>>(pm, ps, u_emb, ent, crel, out);
}

// Round 10
// 2303.724 us; speedup vs baseline: 1.4638x; 1.4638x over previous
//
#include <hip/hip_runtime.h>
#include <hip/hip_bf16.h>
#include <math.h>

#define NNODE 200000
#define EMBD  128
#define TT    32
#define EE    100000
#define AA    4096
#define BB    2048
#define USERN 150000
#define COMPN 49998
#define NPAD  50048     // 391*128
#define NT2   391       // lse n-tiles of 128
#define NT2P  392
#define WLMAX 100096    // >= max touched rows/step, mult of 8
#define GATHB (WLMAX / 8)
#define BLKT  196                         // scan blocks per timestep
#define TNODE (BLKT * 1024)               // 200704 padded nodes per t
#define SCAN_N ((long)TT * TNODE)         // 6,422,528
#define SCAN_BLKS (TT * BLKT)             // 6272

typedef __attribute__((ext_vector_type(8))) short short8;
typedef __attribute__((ext_vector_type(4))) float f32x4;
typedef unsigned short ushort_t;

__device__ __forceinline__ ushort_t f2bf(float f) {
    unsigned u = __float_as_uint(f);
    unsigned r = (u + 0x7fffu + ((u >> 16) & 1u)) >> 16;   // RNE
    return (ushort_t)r;
}
__device__ __forceinline__ unsigned pack2bf(float lo, float hi) {
    return ((unsigned)f2bf(hi) << 16) | (unsigned)f2bf(lo);
}
__device__ __forceinline__ float bflo(unsigned p) { return __uint_as_float(p << 16); }
__device__ __forceinline__ float bfhi(unsigned p) { return __uint_as_float(p & 0xffff0000u); }
__device__ __forceinline__ float bf2f(ushort_t b) { return __uint_as_float((unsigned)b << 16); }
__device__ __forceinline__ float sig(float x) { return 1.f / (1.f + __expf(-x)); }

// ---------------- init A: node16 convert, zero deg/aslot/out ----------------
__global__ void init_a(const float4* __restrict__ ent, ushort_t* __restrict__ node16,
                       int* __restrict__ deg, int* __restrict__ aslot,
                       float* __restrict__ out) {
    const long NV = (long)NNODE * EMBD / 4;
    long i0 = (long)blockIdx.x * blockDim.x + threadIdx.x;
    long stride = (long)gridDim.x * blockDim.x;
    uint2* n2 = (uint2*)node16;
    for (long i = i0; i < NV; i += stride) {
        float4 v = ent[i];
        n2[i] = make_uint2(pack2bf(v.x, v.y), pack2bf(v.z, v.w));
    }
    for (long i = i0; i < SCAN_N; i += stride) deg[i] = 0;
    for (long i = i0; i < NNODE; i += stride) aslot[i] = 0;
    if (i0 == 0) out[0] = 0.f;
}

// ---------------- once: convert weights/biases/comp emb; stamp act step0 ----------------
__global__ void convert_kernel(const float* __restrict__ Wih, const float* __restrict__ Whh,
                               const float* __restrict__ bih, const float* __restrict__ bhh,
                               const float* __restrict__ ent, const int* __restrict__ act,
                               short* __restrict__ w16, float* __restrict__ bsum,
                               short* __restrict__ c16, int* __restrict__ aslot) {
    long i0 = (long)blockIdx.x * blockDim.x + threadIdx.x;
    long stride = (long)gridDim.x * blockDim.x;
    for (long i = i0; i < 512 * 256; i += stride) {
        int n = i >> 8, k = i & 255;
        float v = (k < 128) ? Wih[(size_t)n * 128 + k] : Whh[(size_t)n * 128 + (k - 128)];
        w16[i] = (short)f2bf(v);
    }
    for (long i = i0; i < 512; i += stride) bsum[i] = bih[i] + bhh[i];
    for (long i = i0; i < (long)NPAD * 128; i += stride) {
        long r = i >> 7;
        float v = (r < COMPN) ? ent[(size_t)(USERN + r) * 128 + (i & 127)] : 0.f;
        c16[i] = (short)f2bf(v);
    }
    for (long i = i0; i < AA; i += stride) aslot[act[i]] = (1 << 12) | (int)i;
}

// ---------------- once: histogram edges per (t,dst) ----------------
__global__ void hist_kernel(const int* __restrict__ edst_all, int* __restrict__ deg) {
    int i = blockIdx.x * 256 + threadIdx.x;            // < TT*EE
    int t = i / EE;
    atomicAdd(&deg[(long)t * TNODE + edst_all[i]], 1);
}

// ---------------- once: scan pass 1 (block sums for rs + nonzero counts) ----------------
__global__ __launch_bounds__(256) void scan1(const int* __restrict__ deg,
                                             int* __restrict__ rs, int* __restrict__ bsums,
                                             int* __restrict__ wlb) {
    __shared__ int sh[256];
    long base = (long)blockIdx.x * 1024;
    int tid = threadIdx.x;
    long idx = base + tid * 4;
    int4 v = *(const int4*)&deg[idx];
    int s0 = v.x, s1 = s0 + v.y, s2 = s1 + v.z, s3 = s2 + v.w;
    sh[tid] = s3; __syncthreads();
    for (int off = 1; off < 256; off <<= 1) {
        int t2 = (tid >= off) ? sh[tid - off] : 0; __syncthreads();
        sh[tid] += t2; __syncthreads();
    }
    int excl = tid ? sh[tid - 1] : 0;
    int4 o; o.x = excl; o.y = excl + s0; o.z = excl + s1; o.w = excl + s2;
    *(int4*)&rs[idx] = o;
    if (tid == 255) bsums[blockIdx.x] = sh[255];
    __syncthreads();
    int cz = (v.x > 0) + (v.y > 0) + (v.z > 0) + (v.w > 0);
    sh[tid] = cz; __syncthreads();
    for (int off = 1; off < 256; off <<= 1) {
        int t2 = (tid >= off) ? sh[tid - off] : 0; __syncthreads();
        sh[tid] += t2; __syncthreads();
    }
    if (tid == 255) wlb[blockIdx.x] = sh[255];
}

// ---------------- once: scan pass 2 (global bsums scan + per-t wlb scan) ----------------
__global__ __launch_bounds__(256) void scan2(int* __restrict__ bsums, int* __restrict__ wlb,
                                             int* __restrict__ wl_n) {
    __shared__ int sh[256];
    __shared__ int roff;
    int tid = threadIdx.x;
    if (tid == 0) roff = 0;
    __syncthreads();
    for (int c = 0; c < SCAN_BLKS; c += 256) {
        int v = (c + tid < SCAN_BLKS) ? bsums[c + tid] : 0;
        sh[tid] = v; __syncthreads();
        for (int off = 1; off < 256; off <<= 1) {
            int t2 = (tid >= off) ? sh[tid - off] : 0; __syncthreads();
            sh[tid] += t2; __syncthreads();
        }
        int excl = (tid ? sh[tid - 1] : 0) + roff;
        int tot = sh[255];
        if (c + tid < SCAN_BLKS) bsums[c + tid] = excl;
        __syncthreads();
        if (tid == 0) roff += tot;
        __syncthreads();
    }
    for (int t = 0; t < TT; ++t) {
        int v = (tid < BLKT) ? wlb[t * BLKT + tid] : 0;
        sh[tid] = v; __syncthreads();
        for (int off = 1; off < 256; off <<= 1) {
            int t2 = (tid >= off) ? sh[tid - off] : 0; __syncthreads();
            sh[tid] += t2; __syncthreads();
        }
        if (tid < BLKT) wlb[t * BLKT + tid] = (tid ? sh[tid - 1] : 0);
        if (tid == 0) wl_n[t] = sh[255];
        __syncthreads();
    }
}

// ---------------- once: finalize rs, copy cursors, compact worklists (NO atomics) --------
__global__ __launch_bounds__(256) void scan3(const int* __restrict__ deg, int* __restrict__ rs,
                                             const int* __restrict__ bsums, int* __restrict__ cur,
                                             const int* __restrict__ wlb, int* __restrict__ wl) {
    __shared__ int sh[256];
    int blk = blockIdx.x;
    long base = (long)blk * 1024;
    int off = bsums[blk];
    int tid = threadIdx.x;
    long idx = base + tid * 4;
    int4 r = *(int4*)&rs[idx];
    r.x += off; r.y += off; r.z += off; r.w += off;
    *(int4*)&rs[idx] = r;
    *(int4*)&cur[idx] = r;
    int4 d = *(const int4*)&deg[idx];
    int f0 = d.x > 0, f1 = d.y > 0, f2 = d.z > 0, f3 = d.w > 0;
    sh[tid] = f0 + f1 + f2 + f3; __syncthreads();
    for (int o2 = 1; o2 < 256; o2 <<= 1) {
        int t2 = (tid >= o2) ? sh[tid - o2] : 0; __syncthreads();
        sh[tid] += t2; __syncthreads();
    }
    int excl = tid ? sh[tid - 1] : 0;
    int t0 = blk / BLKT;
    int vbase = (blk - t0 * BLKT) * 1024 + tid * 4;     // node id within t
    int wp = t0 * WLMAX + wlb[blk] + excl;
    if (f0) wl[wp++] = vbase + 0;
    if (f1) wl[wp++] = vbase + 1;
    if (f2) wl[wp++] = vbase + 2;
    if (f3) wl[wp++] = vbase + 3;
}

// ---------------- once: scatter src ids into CSR lists ----------------
__global__ void scatter_kernel(const int* __restrict__ esrc_all, const int* __restrict__ edst_all,
                               int* __restrict__ cur, int* __restrict__ eidx) {
    int i = blockIdx.x * 256 + threadIdx.x;            // < TT*EE
    int t = i / EE;
    int pos = atomicAdd(&cur[(long)t * TNODE + edst_all[i]], 1);
    eidx[pos] = esrc_all[i];
}

// ---------------- per-step K1: gather sums || snapshot(t-1) || stamp t+1 ----------------
__global__ __launch_bounds__(512) void gather_snap(const int* __restrict__ wl,
                                                   const int* __restrict__ wl_n,
                                                   const int* __restrict__ rs,
                                                   const int* __restrict__ deg,
                                                   const int* __restrict__ eidx,
                                                   const ushort_t* __restrict__ node16,
                                                   int* __restrict__ aslot,
                                                   ushort_t* __restrict__ aggW,
                                                   float* __restrict__ aggA,
                                                   const int* __restrict__ su,
                                                   const int* __restrict__ st,
                                                   float* __restrict__ u_emb,
                                                   ushort_t* __restrict__ u16,
                                                   const int* __restrict__ act_all, int t) {
    int blk = blockIdx.x, tid = threadIdx.x;
    if (blk < GATHB) {
        int p = blk * 8 + (tid >> 6);
        if (p >= wl_n[t]) return;
        int lane = tid & 63;
        int v = wl[(size_t)t * WLMAX + p];
        long fi = (long)t * TNODE + v;
        int dg = deg[fi];
        int s0 = rs[fi];
        float sx = 0.f, sy = 0.f;
        for (int j = 0; j < dg; ++j) {
            int s = eidx[s0 + j];
            unsigned pair = ((const unsigned*)node16)[(size_t)s * 64 + lane];
            sx += bflo(pair); sy += bfhi(pair);
        }
        int a = aslot[v];
        if ((a >> 12) == t + 1) {
            *(float2*)&aggA[(size_t)(a & 4095) * 128 + lane * 2] = make_float2(sx, sy);
        } else {
            ((unsigned*)aggW)[(size_t)p * 64 + lane] = pack2bf(sx, sy);
        }
    } else if (blk < GATHB + 256) {
        if (t == 0) return;
        int b = (blk - GATHB) * 8 + (tid >> 6);
        int lane = tid & 63;
        if (st[b] == t - 1) {
            unsigned pair = ((const unsigned*)node16)[(size_t)su[b] * 64 + lane];
            ((unsigned*)u16)[(size_t)b * 64 + lane] = pair;
            *(float2*)&u_emb[(size_t)b * 128 + lane * 2] = make_float2(bflo(pair), bfhi(pair));
        }
    } else {
        if (t + 1 >= TT) return;
        int i = (blk - GATHB - 256) * 512 + tid;
        if (i < AA) aslot[act_all[(size_t)(t + 1) * AA + i]] = ((t + 2) << 12) | i;
    }
}

// ---------------- per-step K2: [gates MFMA + LSTM epi] (blk<256) || apply (rest) ----------
__global__ __launch_bounds__(512) void apply_gates(const int* __restrict__ wl,
                                                   const int* __restrict__ wl_n,
                                                   const int* __restrict__ deg,
                                                   const int* __restrict__ aslot,
                                                   const ushort_t* __restrict__ aggW,
                                                   const float* __restrict__ aggA,
                                                   ushort_t* node16,
                                                   const short* __restrict__ w16,
                                                   const float* __restrict__ bsum,
                                                   const int* __restrict__ act_t,
                                                   const float* __restrict__ c0, int t) {
    __shared__ ushort_t XH[16 * 256];   // 8 KB, XOR-swizzled 16B chunks
    int blk = blockIdx.x, tid = threadIdx.x;
    if (blk < 256) {
        int m0 = blk * 16;
        {
            int row = tid >> 5, j = tid & 31, ch = j & 15;
            int v = act_t[m0 + row];
            int sw = ch ^ (row & 7);
            uint4 nd = *(const uint4*)(node16 + (size_t)v * 128 + ch * 8);
            if (j < 16) {
                int dg = deg[(long)t * TNODE + v];
                uint4 xx = nd;
                if (dg > 0) {
                    float rc = 1.f / dg;
                    float4 A0 = *(const float4*)&aggA[(size_t)(m0 + row) * 128 + ch * 8];
                    float4 A1 = *(const float4*)&aggA[(size_t)(m0 + row) * 128 + ch * 8 + 4];
                    xx.x = pack2bf(bflo(nd.x) + A0.x * rc, bfhi(nd.x) + A0.y * rc);
                    xx.y = pack2bf(bflo(nd.y) + A0.z * rc, bfhi(nd.y) + A0.w * rc);
                    xx.z = pack2bf(bflo(nd.z) + A1.x * rc, bfhi(nd.z) + A1.y * rc);
                    xx.w = pack2bf(bflo(nd.w) + A1.z * rc, bfhi(nd.w) + A1.w * rc);
                }
                *(uint4*)((char*)XH + row * 512 + (sw << 4)) = xx;
            } else {
                *(uint4*)((char*)XH + row * 512 + ((16 + sw) << 4)) = nd;   // prev_h
            }
        }
        __syncthreads();
        int w = tid >> 6, lane = tid & 63;
        int la = lane & 15, lb = lane >> 4;
        f32x4 acc[4] = {};
#pragma unroll
        for (int kc = 0; kc < 8; ++kc) {
            int cc = kc * 4 + lb;
            int sc = (cc & 16) | ((cc & 15) ^ (la & 7));
            short8 af = *(const short8*)((char*)XH + la * 512 + (sc << 4));
#pragma unroll
            for (int s = 0; s < 4; ++s) {
                int n = s * 128 + w * 16 + la;
                short8 bf = *(const short8*)&w16[(size_t)n * 256 + kc * 32 + lb * 8];
                acc[s] = __builtin_amdgcn_mfma_f32_16x16x32_bf16(af, bf, acc[s], 0, 0, 0);
            }
        }
        int d = w * 16 + la;
        float b_i = bsum[d], b_f = bsum[128 + d], b_g = bsum[256 + d], b_o = bsum[384 + d];
#pragma unroll
        for (int r = 0; r < 4; ++r) {
            int lrow = lb * 4 + r;
            int v = act_t[m0 + lrow];
            float gi = acc[0][r] + b_i;
            float gf = acc[1][r] + b_f;
            float gg = acc[2][r] + b_g;
            float go = acc[3][r] + b_o;
            float pc = c0[(size_t)v * 128 + d];      // each node active at most once -> prev_c = c0
            float c_ = sig(gf) * pc + sig(gi) * tanhf(gg);
            float h_ = sig(go) * tanhf(c_);
            node16[(size_t)v * 128 + d] = f2bf(h_);
        }
    } else {
        int p = (blk - 256) * 8 + (tid >> 6);
        if (p >= wl_n[t]) return;
        int lane = tid & 63;
        int v = wl[(size_t)t * WLMAX + p];
        int a = aslot[v];
        if ((a >> 12) == t + 1) return;              // act row handled by gates
        int dg = deg[(long)t * TNODE + v];
        float rc = 1.f / dg;
        unsigned wv = ((const unsigned*)aggW)[(size_t)p * 64 + lane];
        unsigned n = ((unsigned*)node16)[(size_t)v * 64 + lane];
        ((unsigned*)node16)[(size_t)v * 64 + lane] =
            pack2bf(bflo(n) + bflo(wv) * rc, bfhi(n) + bfhi(wv) * rc);
    }
}

// ---------------- post-loop: snapshot t=31 ----------------
__global__ __launch_bounds__(256) void snap31(const ushort_t* __restrict__ node16,
                                              const int* __restrict__ su,
                                              const int* __restrict__ st,
                                              float* __restrict__ u_emb,
                                              ushort_t* __restrict__ u16) {
    int b = blockIdx.x * 2 + threadIdx.x / 128;
    int d = threadIdx.x % 128;
    if (st[b] == TT - 1) {
        ushort_t hv = node16[(size_t)su[b] * 128 + d];
        u16[(size_t)b * 128 + d] = hv;
        u_emb[(size_t)b * 128 + d] = bf2f(hv);
    }
}

// ---------------- final: bf16 MFMA LSE partials, LDS-staged B, tile-major partials ----------
__global__ __launch_bounds__(512) void lse_mfma(const short* __restrict__ u16,
                                                const short* __restrict__ c16,
                                                float* __restrict__ pm, float* __restrict__ ps) {
    __shared__ short Bs[128 * 128];   // 32 KB
    int n0 = blockIdx.x * 128;
    int tid = threadIdx.x;
    const uint4* gsrc = (const uint4*)&c16[(size_t)n0 * 128];
#pragma unroll
    for (int j = 0; j < 4; ++j) {
        int c = j * 512 + tid;
        int r = c >> 4, cc = c & 15;
        *(uint4*)((char*)Bs + r * 256 + ((cc ^ (r & 7)) << 4)) = gsrc[c];
    }
    __syncthreads();

    int w = tid >> 6;
    int lane = tid & 63;
    int la = lane & 15, lb = lane >> 4;
    for (int mt = blockIdx.y * 4; mt < blockIdx.y * 4 + 4; ++mt) {
        int m_a = mt * 128 + w * 16 + la;
        f32x4 acc[8] = {};
#pragma unroll
        for (int kc = 0; kc < 4; ++kc) {
            short8 af = *(const short8*)&u16[(size_t)m_a * 128 + kc * 32 + lb * 8];
#pragma unroll
            for (int s = 0; s < 8; ++s) {
                int nl = s * 16 + la;
                short8 bf = *(const short8*)((const char*)Bs + nl * 256 +
                                             (((kc * 4 + lb) ^ (nl & 7)) << 4));
                acc[s] = __builtin_amdgcn_mfma_f32_16x16x32_bf16(af, bf, acc[s], 0, 0, 0);
            }
        }
#pragma unroll
        for (int r = 0; r < 4; ++r) {
            int row = mt * 128 + w * 16 + lb * 4 + r;
            float mx = -3.4e38f;
#pragma unroll
            for (int s = 0; s < 8; ++s)
                if (n0 + s * 16 + la < COMPN) mx = fmaxf(mx, acc[s][r]);
#pragma unroll
            for (int off = 1; off < 16; off <<= 1) mx = fmaxf(mx, __shfl_xor(mx, off));
            float sm = 0.f;
#pragma unroll
            for (int s = 0; s < 8; ++s)
                if (n0 + s * 16 + la < COMPN) sm += __expf(acc[s][r] - mx);
#pragma unroll
            for (int off = 1; off < 16; off <<= 1) sm += __shfl_xor(sm, off);
            if (la == 0) {
                pm[(size_t)blockIdx.x * BB + row] = mx;
                ps[(size_t)blockIdx.x * BB + row] = sm;
            }
        }
    }
}

// ---------------- final: wave-per-row merge + pos dot + loss ----------------
__global__ __launch_bounds__(256) void merge_final(const float* __restrict__ pm,
                                                   const float* __restrict__ ps,
                                                   const float* __restrict__ u_emb,
                                                   const float* __restrict__ ent,
                                                   const int* __restrict__ crel,
                                                   float* __restrict__ out) {
    int row = blockIdx.x * 4 + (threadIdx.x >> 6);
    int lane = threadIdx.x & 63;
    float m = -3.4e38f, s = 0.f;
    for (int c = lane; c < NT2; c += 64) {
        float mi = pm[(size_t)c * BB + row];
        float si = ps[(size_t)c * BB + row];
        float mn = fmaxf(m, mi);
        s = s * __expf(m - mn) + si * __expf(mi - mn);
        m = mn;
    }
#pragma unroll
    for (int off = 1; off < 64; off <<= 1) {
        float mo = __shfl_xor(m, off);
        float so = __shfl_xor(s, off);
        float mn = fmaxf(m, mo);
        s = s * __expf(m - mn) + so * __expf(mo - mn);
        m = mn;
    }
    float2 uv = *(const float2*)&u_emb[(size_t)row * 128 + lane * 2];
    float2 cv = *(const float2*)&ent[(size_t)(USERN + crel[row]) * 128 + lane * 2];
    float p = uv.x * cv.x + uv.y * cv.y;
#pragma unroll
    for (int off = 1; off < 64; off <<= 1) p += __shfl_xor(p, off);
    if (lane == 0) atomicAdd(out, m + logf(s) - p);
}

extern "C" void kernel_launch(void* const* d_in, const int* in_sizes, int n_in,
                              void* d_out, int out_size, void* d_ws, size_t ws_size,
                              hipStream_t stream) {
    const float* ent  = (const float*)d_in[0];
    const float* c0   = (const float*)d_in[1];
    const float* Wih  = (const float*)d_in[2];
    const float* Whh  = (const float*)d_in[3];
    const float* bih  = (const float*)d_in[4];
    const float* bhh  = (const float*)d_in[5];
    const int* esrc   = (const int*)d_in[6];
    const int* edst   = (const int*)d_in[7];
    const int* act    = (const int*)d_in[8];
    const int* susr   = (const int*)d_in[9];
    const int* stime  = (const int*)d_in[10];
    const int* crel   = (const int*)d_in[11];
    float* out = (float*)d_out;

    float* ws = (float*)d_ws;
    size_t o = 0;
    ushort_t* node16 = (ushort_t*)(ws + o); o += (size_t)NNODE * EMBD / 2;   // 51.2 MB
    int* deg  = (int*)(ws + o); o += SCAN_N;                                  // 25.7 MB
    int* rs   = (int*)(ws + o); o += SCAN_N;                                  // 25.7 MB
    int* cur  = (int*)(ws + o); o += SCAN_N;                                  // 25.7 MB
    int* eidx = (int*)(ws + o); o += (size_t)TT * EE;                         // 12.8 MB
    int* wl   = (int*)(ws + o); o += (size_t)TT * WLMAX;                      // 12.8 MB
    int* wl_n = (int*)(ws + o); o += 64;
    int* bsums = (int*)(ws + o); o += SCAN_BLKS;
    int* wlb  = (int*)(ws + o); o += SCAN_BLKS;
    int* aslot = (int*)(ws + o); o += NNODE;
    ushort_t* aggW = (ushort_t*)(ws + o); o += (size_t)WLMAX * 128 / 2;       // 25.6 MB
    float* aggA = ws + o; o += (size_t)AA * 128;                              // 2 MB
    float* u_emb = ws + o; o += (size_t)BB * 128;
    ushort_t* u16 = (ushort_t*)(ws + o); o += (size_t)BB * 128 / 2;
    short* w16 = (short*)(ws + o); o += (size_t)512 * 256 / 2;
    float* bsum = ws + o; o += 512;
    short* c16 = (short*)(ws + o); o += (size_t)NPAD * 128 / 2;
    // lse partials reuse cur (idle post-loop)
    float* pm = (float*)cur;
    float* ps = pm + (size_t)BB * NT2P;

    // ---- one-time build ----
    init_a<<<4096, 256, 0, stream>>>((const float4*)ent, node16, deg, aslot, out);
    convert_kernel<<<2048, 256, 0, stream>>>(Wih, Whh, bih, bhh, ent, act, w16, bsum, c16, aslot);
    hist_kernel<<<TT * EE / 256, 256, 0, stream>>>(edst, deg);
    scan1<<<SCAN_BLKS, 256, 0, stream>>>(deg, rs, bsums, wlb);
    scan2<<<1, 256, 0, stream>>>(bsums, wlb, wl_n);
    scan3<<<SCAN_BLKS, 256, 0, stream>>>(deg, rs, bsums, cur, wlb, wl);
    scatter_kernel<<<TT * EE / 256, 256, 0, stream>>>(esrc, edst, cur, eidx);

    // ---- time loop: 2 launches/step ----
    for (int t = 0; t < TT; ++t) {
        const int* act_t = act + (size_t)t * AA;
        gather_snap<<<GATHB + 256 + 8, 512, 0, stream>>>(wl, wl_n, rs, deg, eidx, node16,
                                                         aslot, aggW, aggA, susr, stime,
                                                         u_emb, u16, act, t);
        apply_gates<<<256 + GATHB, 512, 0, stream>>>(wl, wl_n, deg, aslot, aggW, aggA,
                                                     node16, w16, bsum, act_t, c0, t);
    }

    snap31<<<BB / 2, 256, 0, stream>>>(node16, susr, stime, u_emb, u16);
    lse_mfma<<<dim3(NT2, 4), 512, 0, stream>>>((const short*)u16, c16, pm, ps);
    merge_final<<<BB / 4, 256, 0, stream>>>(pm, ps, u_emb, ent, crel, out);
}